// Round 11
// baseline (175.276 us; speedup 1.0000x reference)
//
#include <hip/hip_runtime.h>
#include <stdint.h>

// DynamicSparseLinearAttention on MI355X.
// N=4, L=8192, H=8, D=V=128. Layout [n][l][h][d], row stride H*D = 1024 floats.
//
// Lessons: (R4) atomics write through L2 -> never. (R5) small grids starve the
// chip. (R6) per-lane 16B loads at 4KB stride thrash L2; LDS staging with
// coalesced reads is mandatory. (R8) scalar LDS transpose reads cap at 2.4TB/s
// -> stage transposed+bf16-packed, frag reads = ds_read_b128. (R10) __syncthreads
// lowers to s_waitcnt vmcnt(0) -> drains the prefetch queue at every barrier,
// defeating any software pipeline; use raw s_barrier with lgkmcnt(0)-only drain
// so global loads stay in flight (counted vmcnt at the consumer, T4).
//
// 3 launches:
//  kv_direct: fused retile+GEMM. Grid (CH=16,8,4)=512 blocks x 512 thr (8 waves
//             = 2d x 4v). Pipeline: regs P/Q hold steps t+2/t+3 in flight; LDS
//             buffers A/B alternate; one lgkm-only barrier per substep. LDS
//             [d][s2^f(d)], SP=20 -> b64 writes ~8 bank-pairs, b128 reads 2-way.
//             Private fp32 partials, write-once. Ksum via ones-MFMA on wc==0.
//  kv_merge:  sum CH partials -> kvb bf16 [nh][v][d] + ksumg.
//  attn_out:  Q staged to LDS bf16 (row*17 padded chunks), score during staging
//             (fp32 + shfl_xor), B-frags direct from L2-hot kvb. One barrier.

#define LSEQ 8192
#define NHD  1024   // H*D
#define SP   20     // LDS dwords per d-row: 16 s-pair slots + 4 pad

typedef __attribute__((ext_vector_type(4))) float f32x4;
typedef __attribute__((ext_vector_type(8))) short bf16x8;
typedef unsigned short ushort_t;

static __device__ __forceinline__ unsigned short f2bf(float x) {
  union { float f; uint32_t u; } v; v.f = x;
  uint32_t r = v.u + 0x7FFFu + ((v.u >> 16) & 1u);  // RNE
  return (unsigned short)(r >> 16);
}
static __device__ __forceinline__ uint32_t pack_bf(float a, float b) {
  return (uint32_t)f2bf(a) | ((uint32_t)f2bf(b) << 16);
}
static __device__ __forceinline__ float featmap(float x) {
  // elu(x)+1 = x+1 (x>0) else exp(x)
  return x > 0.f ? x + 1.f : __expf(x);
}

// Barrier that does NOT drain vmcnt: LDS-only wait + raw s_barrier. Global
// loads issued before it remain in flight; the compiler inserts counted
// vmcnt(N) where the destination registers are actually consumed.
#define BAR_LGKM() asm volatile("s_waitcnt lgkmcnt(0)\n\ts_barrier" ::: "memory")

// ---------------- Phase 1: fused retile + KV GEMM, 2-deep pipeline ----------
// Grid (CH, 8 h, 4 n), 512 thr = 8 waves = 2 wr(d64) x 4 wc(v32).
__global__ __launch_bounds__(512, 4) void kv_direct(const float* __restrict__ keys,
                                                    const float* __restrict__ values,
                                                    float* __restrict__ kvp,
                                                    float* __restrict__ kspart) {
  __shared__ uint32_t klsA[128 * SP];
  __shared__ uint32_t vlsA[128 * SP];
  __shared__ uint32_t klsB[128 * SP];
  __shared__ uint32_t vlsB[128 * SP];
  const int tid = threadIdx.x;
  const int chunk = blockIdx.x, CH = gridDim.x;
  const int h = blockIdx.y, n = blockIdx.z, nh = n * 8 + h;
  const int lane = tid & 63, w = tid >> 6;
  const int wr = w >> 2, wc = w & 3;
  const int lr = lane & 15, lg = lane >> 4;
  const int sPer = LSEQ / CH;        // 512 at CH=16
  const int steps = sPer / 32;       // 16 at CH=16 (always even)

  const size_t gb = ((size_t)n * LSEQ + (size_t)chunk * sPer) * NHD + h * 128;
  const float* gk = keys + gb;
  const float* gv = values + gb;

  // staging role: wave w owns s = 4w..4w+3; lane owns d-pair (2*lane, 2*lane+1)
  const int a = lane;
  const int fsw = 4 * ((a >> 2) & 3);          // = 4*((d>>3)&3) for d=2a,2a+1
  const int wslot = (2 * w) ^ fsw;
  const int wbase0 = (2 * a) * SP + wslot;
  const int wbase1 = (2 * a + 1) * SP + wslot;

  f32x4 acc[4][2] = {};
  f32x4 ak[4] = {};
  bf16x8 ones;
  { uint32_t* u = (uint32_t*)&ones; u[0] = u[1] = u[2] = u[3] = 0x3F803F80u; }

#define ISSUE(KR, VR, T)                                        \
  do {                                                          \
    _Pragma("unroll") for (int j = 0; j < 4; ++j) {             \
      size_t off = (size_t)((T) * 32 + 4 * w + j) * NHD + 2 * a;\
      KR[j] = *(const float2*)(gk + off);                       \
      VR[j] = *(const float2*)(gv + off);                       \
    }                                                           \
  } while (0)

#define STAGE(KLS, VLS, KR, VR)                                 \
  do {                                                          \
    uint2 kd0, kd1, vd0, vd1;                                   \
    kd0.x = pack_bf(featmap(KR[0].x), featmap(KR[1].x));        \
    kd0.y = pack_bf(featmap(KR[2].x), featmap(KR[3].x));        \
    kd1.x = pack_bf(featmap(KR[0].y), featmap(KR[1].y));        \
    kd1.y = pack_bf(featmap(KR[2].y), featmap(KR[3].y));        \
    vd0.x = pack_bf(VR[0].x, VR[1].x);                          \
    vd0.y = pack_bf(VR[2].x, VR[3].x);                          \
    vd1.x = pack_bf(VR[0].y, VR[1].y);                          \
    vd1.y = pack_bf(VR[2].y, VR[3].y);                          \
    *(uint2*)&KLS[wbase0] = kd0;                                \
    *(uint2*)&KLS[wbase1] = kd1;                                \
    *(uint2*)&VLS[wbase0] = vd0;                                \
    *(uint2*)&VLS[wbase1] = vd1;                                \
  } while (0)

#define FRAGS_MFMA(KLS, VLS)                                                       \
  do {                                                                             \
    bf16x8 af[4], bfr[2];                                                          \
    _Pragma("unroll") for (int fr = 0; fr < 4; ++fr) {                             \
      int d = wr * 64 + fr * 16 + lr;                                              \
      af[fr] = *(const bf16x8*)&KLS[d * SP + ((4 * lg) ^ (4 * ((d >> 3) & 3)))];   \
    }                                                                              \
    _Pragma("unroll") for (int fc = 0; fc < 2; ++fc) {                             \
      int v = wc * 32 + fc * 16 + lr;                                              \
      bfr[fc] = *(const bf16x8*)&VLS[v * SP + ((4 * lg) ^ (4 * ((v >> 3) & 3)))];  \
    }                                                                              \
    _Pragma("unroll") for (int fr = 0; fr < 4; ++fr)                               \
      _Pragma("unroll") for (int fc = 0; fc < 2; ++fc)                             \
        acc[fr][fc] =                                                              \
            __builtin_amdgcn_mfma_f32_16x16x32_bf16(af[fr], bfr[fc], acc[fr][fc], 0, 0, 0); \
    if (wc == 0) {                                                                 \
      _Pragma("unroll") for (int fr = 0; fr < 4; ++fr)                             \
        ak[fr] = __builtin_amdgcn_mfma_f32_16x16x32_bf16(af[fr], ones, ak[fr], 0, 0, 0); \
    }                                                                              \
  } while (0)

  float2 krP[4], vrP[4], krQ[4], vrQ[4];
  ISSUE(krP, vrP, 0);
  ISSUE(krQ, vrQ, 1);

  for (int t = 0; t < steps; t += 2) {
    // even substep: P -> A   (consuming krP waits on counted vmcnt only)
    STAGE(klsA, vlsA, krP, vrP);
    BAR_LGKM();
    if (t + 2 < steps) ISSUE(krP, vrP, t + 2);
    FRAGS_MFMA(klsA, vlsA);
    // odd substep: Q -> B
    STAGE(klsB, vlsB, krQ, vrQ);
    BAR_LGKM();
    if (t + 3 < steps) ISSUE(krQ, vrQ, t + 3);
    FRAGS_MFMA(klsB, vlsB);
  }
#undef ISSUE
#undef STAGE
#undef FRAGS_MFMA

  // C/D: col(v)=lane&15, row(d)=(lane>>4)*4+j. Private partial, write-once.
  float* dst = kvp + ((size_t)chunk * 32 + nh) * 16384;
#pragma unroll
  for (int fr = 0; fr < 4; ++fr)
#pragma unroll
    for (int fc = 0; fc < 2; ++fc) {
      int d0 = wr * 64 + fr * 16 + lg * 4;
      int v  = wc * 32 + fc * 16 + lr;
      *(float4*)(dst + (size_t)v * 128 + d0) =
          make_float4(acc[fr][fc][0], acc[fr][fc][1], acc[fr][fc][2], acc[fr][fc][3]);
    }
  if (wc == 0 && lr == 0) {
    float* ks = kspart + ((size_t)chunk * 32 + nh) * 128;
#pragma unroll
    for (int fr = 0; fr < 4; ++fr)
      *(float4*)(ks + wr * 64 + fr * 16 + lg * 4) =
          make_float4(ak[fr][0], ak[fr][1], ak[fr][2], ak[fr][3]);
  }
}

// ---------------- Phase 1c: merge partials ----------------
__global__ __launch_bounds__(256) void kv_merge(const float* __restrict__ kvp,
                                                const float* __restrict__ kspart,
                                                ushort_t* __restrict__ kvb,
                                                float* __restrict__ ksumg,
                                                int CH) {
  const int nh = blockIdx.x, q = blockIdx.y, tid = threadIdx.x;
  const size_t off = (size_t)nh * 16384 + q * 4096;
#pragma unroll
  for (int i = 0; i < 4; ++i) {
    size_t idx = off + (size_t)(i * 256 + tid) * 4;
    f32x4 s = {};
    for (int c = 0; c < CH; ++c)
      s += *(const f32x4*)(kvp + (size_t)c * 524288 + idx);
    *(uint2*)(kvb + idx) = make_uint2(pack_bf(s[0], s[1]), pack_bf(s[2], s[3]));
  }
  if (q == 0 && tid < 128) {
    float s = 0.f;
    for (int c = 0; c < CH; ++c) s += kspart[((size_t)c * 32 + nh) * 128 + tid];
    ksumg[nh * 128 + tid] = s;
  }
}

// ---------------- Phase 2: LDS-staged Q + direct-global B ----------------
__global__ __launch_bounds__(256, 4) void attn_out(const float* __restrict__ q,
                                                   const ushort_t* __restrict__ kvb,
                                                   const float* __restrict__ ksumg,
                                                   const float* __restrict__ thrp,
                                                   float* __restrict__ out) {
  __shared__ __align__(16) uint32_t As[128 * 17 * 4];  // 34.8KB
  __shared__ float zrow[128];

  const int tid = threadIdx.x;
  const int mc = blockIdx.x, nh = blockIdx.y;
  const int n = nh >> 3, h = nh & 7;
  const size_t qoff = ((size_t)(n * LSEQ + mc * 128)) * NHD + h * 128;
  const float thr = thrp[0];

  const int c4 = tid & 31;
  const float4 kk = *(const float4*)(ksumg + nh * 128 + c4 * 4);

  // ---- stage Qf -> As (bf16) + fp32 score on the fly ----
#pragma unroll
  for (int it = 0; it < 16; ++it) {
    int rr = it * 8 + (tid >> 5);
    float4 qv = *(const float4*)(q + qoff + (size_t)rr * NHD + c4 * 4);
    float f0 = featmap(qv.x), f1 = featmap(qv.y), f2 = featmap(qv.z), f3 = featmap(qv.w);
    uint32_t* dst = &As[(rr * 17 + (c4 >> 1)) * 4 + (c4 & 1) * 2];
    dst[0] = pack_bf(f0, f1);
    dst[1] = pack_bf(f2, f3);
    float p = f0 * kk.x + f1 * kk.y + f2 * kk.z + f3 * kk.w;
    p += __shfl_xor(p, 1);  p += __shfl_xor(p, 2);  p += __shfl_xor(p, 4);
    p += __shfl_xor(p, 8);  p += __shfl_xor(p, 16);
    if (c4 == 0) {
      float sp = p > thr ? p : 0.f;
      zrow[rr] = 1.f / (sp + 1e-6f);
    }
  }
  __syncthreads();

  // ---- MFMA: A from LDS, B direct from kvb (L2-hot 32KB) ----
  const int lane = tid & 63;
  const int w = tid >> 6;
  const int lr = lane & 15, lg = lane >> 4;
  const ushort_t* kvp = kvb + (size_t)nh * 16384;   // [v][d] bf16

  f32x4 acc0[8] = {};
  f32x4 acc1[8] = {};
#pragma unroll
  for (int ks = 0; ks < 4; ++ks) {
    const int c8 = ks * 4 + lg;
    const int dof = ks * 32 + lg * 8;
    const int r0 = w * 32 + lr;
    bf16x8 a0 = *(const bf16x8*)&As[(r0 * 17 + c8) * 4];
    bf16x8 a1 = *(const bf16x8*)&As[((r0 + 16) * 17 + c8) * 4];
#pragma unroll
    for (int ct = 0; ct < 8; ++ct) {
      bf16x8 bb = *(const bf16x8*)(kvp + (size_t)((ct * 16 + lr) * 128) + dof);
      acc0[ct] = __builtin_amdgcn_mfma_f32_16x16x32_bf16(a0, bb, acc0[ct], 0, 0, 0);
      acc1[ct] = __builtin_amdgcn_mfma_f32_16x16x32_bf16(a1, bb, acc1[ct], 0, 0, 0);
    }
  }

  float z0[4], z1[4];
#pragma unroll
  for (int j = 0; j < 4; ++j) {
    z0[j] = zrow[w * 32 + lg * 4 + j];
    z1[j] = zrow[w * 32 + 16 + lg * 4 + j];
  }
  float* op = out + qoff;
#pragma unroll
  for (int ct = 0; ct < 8; ++ct)
#pragma unroll
    for (int jj = 0; jj < 4; ++jj) {
      int row = w * 32 + lg * 4 + jj;   // C/D: col=lane&15, row=(lane>>4)*4+jj
      op[(size_t)row * NHD + ct * 16 + lr]        = acc0[ct][jj] * z0[jj];
      op[(size_t)(row + 16) * NHD + ct * 16 + lr] = acc1[ct][jj] * z1[jj];
    }
}

extern "C" void kernel_launch(void* const* d_in, const int* in_sizes, int n_in,
                              void* d_out, int out_size, void* d_ws, size_t ws_size,
                              hipStream_t stream) {
  const float* queries   = (const float*)d_in[0];
  const float* keys      = (const float*)d_in[1];
  const float* values    = (const float*)d_in[2];
  const float* threshold = (const float*)d_in[3];
  float* out = (float*)d_out;

  // ws: kvp CH*2MB | kspart CH*16KB | kvb 1MB | ksumg 16KB   (CH=16 -> ~34.9MB)
  int CH = 16;
  while (CH > 1 &&
         (size_t)CH * (524288 + 32 * 128) * 4 + (size_t)32 * 16384 * 2 + 32 * 128 * 4 > ws_size)
    CH >>= 1;
  float* kvp     = (float*)d_ws;
  float* kspart  = kvp + (size_t)CH * 524288;
  ushort_t* kvb  = (ushort_t*)(kspart + (size_t)CH * 32 * 128);
  float* ksumg   = (float*)(kvb + (size_t)32 * 16384);

  kv_direct<<<dim3(CH, 8, 4), 512, 0, stream>>>(keys, values, kvp, kspart);
  kv_merge<<<dim3(32, 4), 256, 0, stream>>>(kvp, kspart, kvb, ksumg, CH);
  attn_out<<<dim3(64, 32), 256, 0, stream>>>(queries, kvb, ksumg, threshold, out);
}